// Round 3
// baseline (319.925 us; speedup 1.0000x reference)
//
#include <hip/hip_runtime.h>
#include <hip/hip_bf16.h>

typedef __bf16 bf16x8 __attribute__((ext_vector_type(8)));
typedef __bf16 bf16x4 __attribute__((ext_vector_type(4)));
typedef float  f32x4  __attribute__((ext_vector_type(4)));

// ---------------------------------------------------------------------------
// neigh_mask dtype detection: bool may arrive as uint8 bytes or int32 words.
// View as int32: any word > 1 => packed uint8 layout. flag: 1=uint8, 0=int32.
// ---------------------------------------------------------------------------
__global__ void detect_mask_kernel(const unsigned* __restrict__ mw, int nwords,
                                   int* __restrict__ flag) {
    int any = 0;
    for (int i = blockIdx.x * blockDim.x + threadIdx.x; i < nwords;
         i += gridDim.x * blockDim.x)
        if (mw[i] > 1u) any = 1;
    if (__any(any)) {
        if ((threadIdx.x & 63) == 0) atomicOr(flag, 1);
    }
}

// f32 -> bf16 table conversion (n divisible by 8; n = V*64)
__global__ void cvt_bf16_kernel(const float* __restrict__ src,
                                __bf16* __restrict__ dst, int n) {
    for (int i = (blockIdx.x * blockDim.x + threadIdx.x) * 8; i < n;
         i += gridDim.x * blockDim.x * 8) {
        f32x4 a = *(const f32x4*)(src + i);
        f32x4 b = *(const f32x4*)(src + i + 4);
        bf16x8 o;
        o[0] = (__bf16)a[0]; o[1] = (__bf16)a[1];
        o[2] = (__bf16)a[2]; o[3] = (__bf16)a[3];
        o[4] = (__bf16)b[0]; o[5] = (__bf16)b[1];
        o[6] = (__bf16)b[2]; o[7] = (__bf16)b[3];
        *(bf16x8*)(dst + i) = o;
    }
}

// ---------------------------------------------------------------------------
// Main kernel: 1 wave per node, 4 waves/block, grid-stride.
// MFMA 16x16x32 bf16 layouts (learn_hip m89):
//   A: row=lane&15, k=(lane>>4)*8+i ; B: col=lane&15, k=(lane>>4)*8+i
//   C/D: col=lane&15, row=(lane>>4)*4+reg
// e_u and h1 live in padded row-major bf16 LDS tiles [32][72] (pitch 144 B):
//   A-frag read  = bf16x8 at row*144 + dblk*64 + (lane>>4)*16 (16B aligned,
//   bank-balanced full-rate); final sum reads eu[k][l] (2-way, free).
// ---------------------------------------------------------------------------
template <int BF16SRC>
__global__ __launch_bounds__(256, 3) void graphrec_agg_kernel(
    const float* __restrict__ u2e, const __bf16* __restrict__ tbl,
    const float* __restrict__ W1, const float* __restrict__ b1,
    const float* __restrict__ W2, const float* __restrict__ b2,
    const float* __restrict__ W3, const float* __restrict__ b3,
    const int* __restrict__ nodes, const int* __restrict__ neigh_idx,
    const void* __restrict__ mask, const int* __restrict__ flag,
    float* __restrict__ out, int N)
{
    __shared__ __align__(16) __bf16 w1f[16][64][8];   // W1 B-frags   16384 B
    __shared__ __align__(16) __bf16 eu16[4][32][72];  // e_u tiles    18432 B
    __shared__ __align__(16) __bf16 h1s[4][32][72];   // h1 tiles     18432 B
    __shared__ __align__(16) __bf16 urep[4][64];      //                512 B
    __shared__ float att_s[4][32];                    //                512 B

    const int tid = threadIdx.x;
    const int w = tid >> 6;        // wave in block
    const int l = tid & 63;        // lane
    const int g = l >> 4;          // 16-lane group
    const int c = l & 15;          // lane within group

    // ---- stage W1 (128x64) as bf16 B-fragments (block-shared) ----
    for (int f = w; f < 16; f += 4) {
        int kt = f >> 2, nt = f & 3;
        int r0 = kt * 32 + g * 8, col = nt * 16 + c;
        bf16x8 t;
        #pragma unroll
        for (int i = 0; i < 8; ++i) t[i] = (__bf16)W1[(r0 + i) * 64 + col];
        *(bf16x8*)&w1f[f][l][0] = t;
    }
    __syncthreads();

    // ---- W2 B-fragments in registers (each lane only needs its own slice) ----
    bf16x8 w2r[8];
    #pragma unroll
    for (int f = 0; f < 8; ++f) {
        int kt = f >> 2, nt = f & 3;
        int r0 = kt * 32 + g * 8, col = nt * 16 + c;
        #pragma unroll
        for (int i = 0; i < 8; ++i) w2r[f][i] = (__bf16)W2[(r0 + i) * 64 + col];
    }

    float b1v[4], b2v[4], w3v[4];
    #pragma unroll
    for (int nt = 0; nt < 4; ++nt) {
        b1v[nt] = b1[nt * 16 + c];
        b2v[nt] = b2[nt * 16 + c];
        w3v[nt] = W3[nt * 16 + c];
    }
    const float b3s = b3[0];
    const int layout8 = *flag;
    const unsigned char* m8p  = (const unsigned char*)mask;
    const int*           m32p = (const int*)mask;

    const int stride = gridDim.x * 4;
    int n = blockIdx.x * 4 + w;

    // prefetched per-node state
    int vidx = 0, un = 0;
    bool mv = false;
    if (n < N) {
        if (l < 32) {
            vidx = neigh_idx[n * 32 + l];
            mv = layout8 ? (m8p[n * 32 + l] != 0) : (m32p[n * 32 + l] != 0);
        }
        un = nodes[n];
    }

    for (; n < N; n += stride) {
        // ---- prefetch next node's indices (hide global latency) ----
        int n2 = n + stride;
        int vidx2 = 0, un2 = 0;
        bool mv2 = false;
        if (n2 < N) {
            if (l < 32) {
                vidx2 = neigh_idx[n2 * 32 + l];
                mv2 = layout8 ? (m8p[n2 * 32 + l] != 0) : (m32p[n2 * 32 + l] != 0);
            }
            un2 = nodes[n2];
        }

        unsigned long long bal = __ballot(mv);

        // ---- center embedding ----
        if (BF16SRC) {
            urep[w][l] = tbl[(size_t)un * 64 + l];
        } else {
            urep[w][l] = (__bf16)u2e[(size_t)un * 64 + l];
        }

        // ---- gather e_u rows into padded bf16 tile ----
        if (BF16SRC) {
            #pragma unroll
            for (int it = 0; it < 4; ++it) {
                int k = it * 8 + (l >> 3);
                int idx = __shfl(vidx, k);
                bf16x8 v = *(const bf16x8*)(tbl + (size_t)idx * 64 + (l & 7) * 8);
                *(bf16x8*)&eu16[w][k][(l & 7) * 8] = v;
            }
        } else {
            #pragma unroll
            for (int it = 0; it < 8; ++it) {
                int k = it * 4 + g;
                int idx = __shfl(vidx, k);
                f32x4 v = *(const f32x4*)(u2e + (size_t)idx * 64 + c * 4);
                bf16x4 bv;
                bv[0] = (__bf16)v[0]; bv[1] = (__bf16)v[1];
                bv[2] = (__bf16)v[2]; bv[3] = (__bf16)v[3];
                *(bf16x4*)&eu16[w][k][c * 4] = bv;
            }
        }

        // ---- layer 1: h1 = relu([e_u | u_rep] @ W1 + b1) ----
        bf16x8 a2 = *(const bf16x8*)&urep[w][g * 8];
        bf16x8 a3 = *(const bf16x8*)&urep[w][32 + g * 8];
        #pragma unroll
        for (int mt = 0; mt < 2; ++mt) {
            const __bf16* arow = &eu16[w][mt * 16 + c][0];
            bf16x8 a0 = *(const bf16x8*)(arow + g * 8);
            bf16x8 a1 = *(const bf16x8*)(arow + 32 + g * 8);
            #pragma unroll
            for (int nt = 0; nt < 4; ++nt) {
                f32x4 cc = {0.f, 0.f, 0.f, 0.f};
                cc = __builtin_amdgcn_mfma_f32_16x16x32_bf16(a0, *(const bf16x8*)&w1f[0 + nt][l][0], cc, 0, 0, 0);
                cc = __builtin_amdgcn_mfma_f32_16x16x32_bf16(a1, *(const bf16x8*)&w1f[4 + nt][l][0], cc, 0, 0, 0);
                cc = __builtin_amdgcn_mfma_f32_16x16x32_bf16(a2, *(const bf16x8*)&w1f[8 + nt][l][0], cc, 0, 0, 0);
                cc = __builtin_amdgcn_mfma_f32_16x16x32_bf16(a3, *(const bf16x8*)&w1f[12 + nt][l][0], cc, 0, 0, 0);
                #pragma unroll
                for (int r = 0; r < 4; ++r) {
                    float hv = fmaxf(cc[r] + b1v[nt], 0.f);
                    h1s[w][mt * 16 + g * 4 + r][nt * 16 + c] = (__bf16)hv;
                }
            }
        }

        // ---- layer 2 + per-lane score partials ----
        float p[2][4];
        #pragma unroll
        for (int mt = 0; mt < 2; ++mt) {
            const __bf16* arow = &h1s[w][mt * 16 + c][0];
            bf16x8 a0 = *(const bf16x8*)(arow + g * 8);
            bf16x8 a1 = *(const bf16x8*)(arow + 32 + g * 8);
            float pr0 = 0.f, pr1 = 0.f, pr2 = 0.f, pr3 = 0.f;
            #pragma unroll
            for (int nt = 0; nt < 4; ++nt) {
                f32x4 cc = {0.f, 0.f, 0.f, 0.f};
                cc = __builtin_amdgcn_mfma_f32_16x16x32_bf16(a0, w2r[0 + nt], cc, 0, 0, 0);
                cc = __builtin_amdgcn_mfma_f32_16x16x32_bf16(a1, w2r[4 + nt], cc, 0, 0, 0);
                pr0 += fmaxf(cc[0] + b2v[nt], 0.f) * w3v[nt];
                pr1 += fmaxf(cc[1] + b2v[nt], 0.f) * w3v[nt];
                pr2 += fmaxf(cc[2] + b2v[nt], 0.f) * w3v[nt];
                pr3 += fmaxf(cc[3] + b2v[nt], 0.f) * w3v[nt];
            }
            p[mt][0] = pr0; p[mt][1] = pr1; p[mt][2] = pr2; p[mt][3] = pr3;
        }

        // ---- reduce score partials over the 16 columns ----
        float s[8];
        #pragma unroll
        for (int m = 0; m < 8; ++m) {
            float v = p[m >> 2][m & 3];
            v += __shfl_xor(v, 1);
            v += __shfl_xor(v, 2);
            v += __shfl_xor(v, 4);
            v += __shfl_xor(v, 8);
            s[m] = v + b3s;
        }

        // ---- masked softmax over k=0..31 (row k = (m>>2)*16 + g*4 + (m&3)) ----
        bool vald[8];
        float m8 = -1e30f;
        #pragma unroll
        for (int m = 0; m < 8; ++m) {
            int k = (m >> 2) * 16 + g * 4 + (m & 3);
            vald[m] = ((bal >> k) & 1ull) != 0;
            if (vald[m]) m8 = fmaxf(m8, s[m]);
        }
        m8 = fmaxf(m8, __shfl_xor(m8, 16));
        m8 = fmaxf(m8, __shfl_xor(m8, 32));
        float es[8], ls = 0.f;
        #pragma unroll
        for (int m = 0; m < 8; ++m) {
            es[m] = vald[m] ? __expf(s[m] - m8) : 0.f;
            ls += es[m];
        }
        ls += __shfl_xor(ls, 16);
        ls += __shfl_xor(ls, 32);
        float inv = (ls > 0.f) ? 1.f / ls : 0.f;
        if (c == 0) {
            #pragma unroll
            for (int m = 0; m < 8; ++m) {
                int k = (m >> 2) * 16 + g * 4 + (m & 3);
                att_s[w][k] = es[m] * inv;
            }
        }

        // ---- out[n][l] = sum_k att[k] * e_u[k][l] ----
        float acc = 0.f;
        #pragma unroll
        for (int k = 0; k < 32; ++k)
            acc += att_s[w][k] * (float)eu16[w][k][l];
        out[(size_t)n * 64 + l] = acc;

        vidx = vidx2; mv = mv2; un = un2;
    }
}

extern "C" void kernel_launch(void* const* d_in, const int* in_sizes, int n_in,
                              void* d_out, int out_size, void* d_ws, size_t ws_size,
                              hipStream_t stream) {
    const float* u2e = (const float*)d_in[0];
    const float* W1  = (const float*)d_in[1];
    const float* b1  = (const float*)d_in[2];
    const float* W2  = (const float*)d_in[3];
    const float* b2  = (const float*)d_in[4];
    const float* W3  = (const float*)d_in[5];
    const float* b3  = (const float*)d_in[6];
    const int* nodes     = (const int*)d_in[7];
    const int* neigh_idx = (const int*)d_in[8];
    const void* mask     = d_in[9];

    const int N  = in_sizes[7];          // nodes
    const int VD = in_sizes[0];          // V*D elements of u2e

    int* flag = (int*)d_ws;
    __bf16* tbl = (__bf16*)((char*)d_ws + 256);
    const size_t needed = 256 + (size_t)VD * sizeof(__bf16);
    const bool use16 = (ws_size >= needed);

    hipMemsetAsync(flag, 0, sizeof(int), stream);
    int nwords = in_sizes[9] / 4;
    detect_mask_kernel<<<128, 256, 0, stream>>>((const unsigned*)mask, nwords, flag);

    if (use16) {
        cvt_bf16_kernel<<<2048, 256, 0, stream>>>(u2e, tbl, VD);
        graphrec_agg_kernel<1><<<768, 256, 0, stream>>>(
            u2e, tbl, W1, b1, W2, b2, W3, b3, nodes, neigh_idx, mask, flag,
            (float*)d_out, N);
    } else {
        graphrec_agg_kernel<0><<<768, 256, 0, stream>>>(
            u2e, (const __bf16*)u2e, W1, b1, W2, b2, W3, b3, nodes, neigh_idx,
            mask, flag, (float*)d_out, N);
    }
}

// Round 4
// 234.077 us; speedup vs baseline: 1.3668x; 1.3668x over previous
//
#include <hip/hip_runtime.h>
#include <hip/hip_bf16.h>

typedef __bf16 bf16x8 __attribute__((ext_vector_type(8)));
typedef __bf16 bf16x4 __attribute__((ext_vector_type(4)));
typedef float  f32x4  __attribute__((ext_vector_type(4)));

// ---------------------------------------------------------------------------
// neigh_mask dtype detection: bool may arrive as uint8 bytes or int32 words.
// View as int32: any word > 1 => packed uint8 layout. flag: 1=uint8, 0=int32.
// ---------------------------------------------------------------------------
__global__ void detect_mask_kernel(const unsigned* __restrict__ mw, int nwords,
                                   int* __restrict__ flag) {
    int any = 0;
    for (int i = blockIdx.x * blockDim.x + threadIdx.x; i < nwords;
         i += gridDim.x * blockDim.x)
        if (mw[i] > 1u) any = 1;
    if (__any(any)) {
        if ((threadIdx.x & 63) == 0) atomicOr(flag, 1);
    }
}

// ---------------------------------------------------------------------------
// Main kernel: 1 wave per node, 4 waves/block, grid-stride, node-pipelined.
// MFMA 16x16x32 bf16 layouts (learn_hip m89):
//   A: row=lane&15, k=(lane>>4)*8+i ; B: col=lane&15, k=(lane>>4)*8+i
//   C/D: col=lane&15, row=(lane>>4)*4+reg
// Pipeline per iteration (node nA):
//   (a) prefetch indices for nA+2*stride (consumed next iter at (c))
//   (b) commit prefetched f32 rows of nA (registers) -> bf16 LDS tile
//   (c) issue row gathers for nA+stride into registers (wait lands at next
//       iter's (b), covered by this iter's full compute)
//   (d) compute: L1 MFMA (reads tile, writes h1 back into SAME tile — e_u
//       rows are dead after their A-frag reads), L2 MFMA, softmax, final
//       weighted sum from the still-live f32 row REGISTERS (no LDS reads).
// ---------------------------------------------------------------------------
__global__ __launch_bounds__(256, 3) void graphrec_agg_kernel(
    const float* __restrict__ u2e,
    const float* __restrict__ W1, const float* __restrict__ b1,
    const float* __restrict__ W2, const float* __restrict__ b2,
    const float* __restrict__ W3, const float* __restrict__ b3,
    const int* __restrict__ nodes, const int* __restrict__ neigh_idx,
    const void* __restrict__ mask, const int* __restrict__ flag,
    float* __restrict__ out, int N)
{
    __shared__ __align__(16) __bf16 w1f[16][64][8];   // W1 B-frags 16384 B
    __shared__ __align__(16) __bf16 tile[4][32][72];  // e_u then h1 18432 B
    __shared__ __align__(16) __bf16 urep[4][64];      //              512 B
    __shared__ float att_s[4][32];                    //              512 B

    const int tid = threadIdx.x;
    const int w = tid >> 6;        // wave in block
    const int l = tid & 63;        // lane
    const int g = l >> 4;          // 16-lane group
    const int c = l & 15;          // lane within group

    // ---- stage W1 (128x64) as bf16 B-fragments (block-shared) ----
    for (int f = w; f < 16; f += 4) {
        int kt = f >> 2, nt = f & 3;
        int r0 = kt * 32 + g * 8, col = nt * 16 + c;
        bf16x8 t;
        #pragma unroll
        for (int i = 0; i < 8; ++i) t[i] = (__bf16)W1[(r0 + i) * 64 + col];
        *(bf16x8*)&w1f[f][l][0] = t;
    }
    __syncthreads();

    // ---- W2 B-fragments in registers ----
    bf16x8 w2r[8];
    #pragma unroll
    for (int f = 0; f < 8; ++f) {
        int kt = f >> 2, nt = f & 3;
        int r0 = kt * 32 + g * 8, col = nt * 16 + c;
        #pragma unroll
        for (int i = 0; i < 8; ++i) w2r[f][i] = (__bf16)W2[(r0 + i) * 64 + col];
    }

    float b1v[4], b2v[4], w3v[4];
    #pragma unroll
    for (int nt = 0; nt < 4; ++nt) {
        b1v[nt] = b1[nt * 16 + c];
        b2v[nt] = b2[nt * 16 + c];
        w3v[nt] = W3[nt * 16 + c];
    }
    const float b3s = b3[0];
    const int layout8 = *flag;
    const unsigned char* m8p  = (const unsigned char*)mask;
    const int*           m32p = (const int*)mask;

    const int stride = gridDim.x * 4;
    int nA = blockIdx.x * 4 + w;
    int nB = nA + stride;

    // ---- prologue: indices for nA and nB ----
    int vidxA = 0, unA = 0; bool mvA = false;
    if (nA < N) {
        if (l < 32) {
            int o = nA * 32 + l;
            vidxA = neigh_idx[o];
            mvA = layout8 ? (m8p[o] != 0) : (m32p[o] != 0);
        }
        unA = nodes[nA];
    }
    int vidxB = 0, unB = 0; bool mvB = false;
    if (nB < N) {
        if (l < 32) {
            int o = nB * 32 + l;
            vidxB = neigh_idx[o];
            mvB = layout8 ? (m8p[o] != 0) : (m32p[o] != 0);
        }
        unB = nodes[nB];
    }

    // ---- prologue: issue row gathers for nA ----
    f32x4 rr[8]; float urv = 0.f;
    if (nA < N) {
        #pragma unroll
        for (int kb = 0; kb < 8; ++kb) {
            int idx = __shfl(vidxA, kb * 4 + g);
            rr[kb] = *(const f32x4*)(u2e + (size_t)idx * 64 + c * 4);
        }
        urv = u2e[(size_t)unA * 64 + l];
    }

    for (; nA < N; nA += stride, nB += stride) {
        // ---- (a) prefetch indices for nC = nA + 2*stride ----
        int nC = nB + stride;
        int vidxC = 0, unC = 0; bool mvC = false;
        if (nC < N) {
            if (l < 32) {
                int o = nC * 32 + l;
                vidxC = neigh_idx[o];
                mvC = layout8 ? (m8p[o] != 0) : (m32p[o] != 0);
            }
            unC = nodes[nC];
        }

        // ---- (b) commit rows of nA to LDS ----
        unsigned long long bal = __ballot(mvA);
        urep[w][l] = (__bf16)urv;
        #pragma unroll
        for (int kb = 0; kb < 8; ++kb) {
            int k = kb * 4 + g;
            bf16x4 bv;
            bv[0] = (__bf16)rr[kb][0]; bv[1] = (__bf16)rr[kb][1];
            bv[2] = (__bf16)rr[kb][2]; bv[3] = (__bf16)rr[kb][3];
            *(bf16x4*)&tile[w][k][c * 4] = bv;
        }

        // ---- (c) issue row gathers for nB (covered by (d)'s compute) ----
        f32x4 rn[8]; float urvn;
        #pragma unroll
        for (int kb = 0; kb < 8; ++kb) {
            int idx = __shfl(vidxB, kb * 4 + g);
            rn[kb] = *(const f32x4*)(u2e + (size_t)idx * 64 + c * 4);
        }
        urvn = u2e[(size_t)unB * 64 + l];

        // ---- (d) compute node nA ----
        // layer 1: h1 = relu([e_u | u_rep] @ W1 + b1); h1 overwrites tile
        bf16x8 a2 = *(const bf16x8*)&urep[w][g * 8];
        bf16x8 a3 = *(const bf16x8*)&urep[w][32 + g * 8];
        #pragma unroll
        for (int mt = 0; mt < 2; ++mt) {
            const __bf16* arow = &tile[w][mt * 16 + c][0];
            bf16x8 a0 = *(const bf16x8*)(arow + g * 8);
            bf16x8 a1 = *(const bf16x8*)(arow + 32 + g * 8);
            #pragma unroll
            for (int nt = 0; nt < 4; ++nt) {
                f32x4 cc = {0.f, 0.f, 0.f, 0.f};
                cc = __builtin_amdgcn_mfma_f32_16x16x32_bf16(a0, *(const bf16x8*)&w1f[0 + nt][l][0], cc, 0, 0, 0);
                cc = __builtin_amdgcn_mfma_f32_16x16x32_bf16(a1, *(const bf16x8*)&w1f[4 + nt][l][0], cc, 0, 0, 0);
                cc = __builtin_amdgcn_mfma_f32_16x16x32_bf16(a2, *(const bf16x8*)&w1f[8 + nt][l][0], cc, 0, 0, 0);
                cc = __builtin_amdgcn_mfma_f32_16x16x32_bf16(a3, *(const bf16x8*)&w1f[12 + nt][l][0], cc, 0, 0, 0);
                #pragma unroll
                for (int r = 0; r < 4; ++r) {
                    float hv = fmaxf(cc[r] + b1v[nt], 0.f);
                    tile[w][mt * 16 + g * 4 + r][nt * 16 + c] = (__bf16)hv;
                }
            }
        }

        // layer 2 + per-lane score partials
        float p[2][4];
        #pragma unroll
        for (int mt = 0; mt < 2; ++mt) {
            const __bf16* arow = &tile[w][mt * 16 + c][0];
            bf16x8 a0 = *(const bf16x8*)(arow + g * 8);
            bf16x8 a1 = *(const bf16x8*)(arow + 32 + g * 8);
            float pr0 = 0.f, pr1 = 0.f, pr2 = 0.f, pr3 = 0.f;
            #pragma unroll
            for (int nt = 0; nt < 4; ++nt) {
                f32x4 cc = {0.f, 0.f, 0.f, 0.f};
                cc = __builtin_amdgcn_mfma_f32_16x16x32_bf16(a0, w2r[0 + nt], cc, 0, 0, 0);
                cc = __builtin_amdgcn_mfma_f32_16x16x32_bf16(a1, w2r[4 + nt], cc, 0, 0, 0);
                pr0 += fmaxf(cc[0] + b2v[nt], 0.f) * w3v[nt];
                pr1 += fmaxf(cc[1] + b2v[nt], 0.f) * w3v[nt];
                pr2 += fmaxf(cc[2] + b2v[nt], 0.f) * w3v[nt];
                pr3 += fmaxf(cc[3] + b2v[nt], 0.f) * w3v[nt];
            }
            p[mt][0] = pr0; p[mt][1] = pr1; p[mt][2] = pr2; p[mt][3] = pr3;
        }

        // reduce score partials over the 16 columns
        float s[8];
        #pragma unroll
        for (int m = 0; m < 8; ++m) {
            float v = p[m >> 2][m & 3];
            v += __shfl_xor(v, 1);
            v += __shfl_xor(v, 2);
            v += __shfl_xor(v, 4);
            v += __shfl_xor(v, 8);
            s[m] = v + b3s;
        }

        // masked softmax over k=0..31 (row k = (m>>2)*16 + g*4 + (m&3))
        bool vald[8];
        float m8 = -1e30f;
        #pragma unroll
        for (int m = 0; m < 8; ++m) {
            int k = (m >> 2) * 16 + g * 4 + (m & 3);
            vald[m] = ((bal >> k) & 1ull) != 0;
            if (vald[m]) m8 = fmaxf(m8, s[m]);
        }
        m8 = fmaxf(m8, __shfl_xor(m8, 16));
        m8 = fmaxf(m8, __shfl_xor(m8, 32));
        float es[8], ls = 0.f;
        #pragma unroll
        for (int m = 0; m < 8; ++m) {
            es[m] = vald[m] ? __expf(s[m] - m8) : 0.f;
            ls += es[m];
        }
        ls += __shfl_xor(ls, 16);
        ls += __shfl_xor(ls, 32);
        float inv = (ls > 0.f) ? 1.f / ls : 0.f;
        if (c == 0) {
            #pragma unroll
            for (int m = 0; m < 8; ++m) {
                int k = (m >> 2) * 16 + g * 4 + (m & 3);
                att_s[w][k] = es[m] * inv;
            }
        }

        // final weighted sum from f32 row registers (no LDS tile reads)
        float o0 = 0.f, o1 = 0.f, o2 = 0.f, o3 = 0.f;
        #pragma unroll
        for (int kb = 0; kb < 8; ++kb) {
            float a = att_s[w][kb * 4 + g];
            o0 += a * rr[kb][0]; o1 += a * rr[kb][1];
            o2 += a * rr[kb][2]; o3 += a * rr[kb][3];
        }
        o0 += __shfl_xor(o0, 16); o0 += __shfl_xor(o0, 32);
        o1 += __shfl_xor(o1, 16); o1 += __shfl_xor(o1, 32);
        o2 += __shfl_xor(o2, 16); o2 += __shfl_xor(o2, 32);
        o3 += __shfl_xor(o3, 16); o3 += __shfl_xor(o3, 32);
        if (g == 0) {
            f32x4 ov = {o0, o1, o2, o3};
            *(f32x4*)(out + (size_t)nA * 64 + c * 4) = ov;
        }

        // ---- (e) rotate pipeline state ----
        #pragma unroll
        for (int kb = 0; kb < 8; ++kb) rr[kb] = rn[kb];
        urv = urvn;
        mvA = mvB;
        vidxB = vidxC; mvB = mvC; unB = unC;
    }
}

extern "C" void kernel_launch(void* const* d_in, const int* in_sizes, int n_in,
                              void* d_out, int out_size, void* d_ws, size_t ws_size,
                              hipStream_t stream) {
    const float* u2e = (const float*)d_in[0];
    const float* W1  = (const float*)d_in[1];
    const float* b1  = (const float*)d_in[2];
    const float* W2  = (const float*)d_in[3];
    const float* b2  = (const float*)d_in[4];
    const float* W3  = (const float*)d_in[5];
    const float* b3  = (const float*)d_in[6];
    const int* nodes     = (const int*)d_in[7];
    const int* neigh_idx = (const int*)d_in[8];
    const void* mask     = d_in[9];

    const int N = in_sizes[7];           // nodes
    int* flag = (int*)d_ws;

    hipMemsetAsync(flag, 0, sizeof(int), stream);
    int nwords = in_sizes[9] / 4;
    detect_mask_kernel<<<128, 256, 0, stream>>>((const unsigned*)mask, nwords, flag);

    graphrec_agg_kernel<<<768, 256, 0, stream>>>(
        u2e, W1, b1, W2, b2, W3, b3, nodes, neigh_idx, mask, flag,
        (float*)d_out, N);
}